// Round 2
// baseline (355.718 us; speedup 1.0000x reference)
//
#include <hip/hip_runtime.h>

// SimpleMovingAverage: history (64, 336, 862, 3) f32 -> out (64, 336, 862, 3).
// The scan is LINEAR in the last-12 window: out[b,t,sc] = sum_k coef[t][k]*x[b,k,sc].
// coef is input-independent -> computed at COMPILE TIME into __constant__ memory.
// Write-BW-bound op: 222 MB out (mandatory), 8 MB in (mandatory); roofline ~37us.
// R1 (resubmit; prior two rounds died on container infra, no data):
//   TT 12->84 (cut redundant window re-reads 28x -> 4x) + non-temporal
//   stores (streaming output must not evict the L2-resident window).

#define Q 12
#define IN_LEN 336
#define OUT_LEN 336
#define NB 64
#define SC2 1293        // SC/2 in float2 units (862*3/2)
#define TT 84           // t-values per thread (336 = 4*84)

struct Coefs { float c[OUT_LEN][Q]; };

// Compile-time evaluation of the recurrence on the 12 basis vectors.
constexpr Coefs make_coefs() {
    Coefs tbl{};
    for (int k = 0; k < Q; ++k) {
        float w[Q] = {};
        w[k] = 1.0f;
        float sum = 1.0f;
        for (int step = 0; step < OUT_LEN; ++step) {
            const int j = step % Q;
            const float m = sum * (1.0f / 12.0f);
            sum += m - w[j];         // drop oldest, append mean
            w[j] = m;
            tbl.c[step][k] = m;
            if (j == Q - 1) {        // re-anchor running sum: kill FP drift
                float s = 0.0f;
                for (int i = 0; i < Q; ++i) s += w[i];
                sum = s;
            }
        }
    }
    return tbl;
}

__constant__ Coefs g_coef = make_coefs();

__global__ __launch_bounds__(256) void
SimpleMovingAverage_22144851378808_kernel(const float2* __restrict__ in,
                                          float2* __restrict__ out) {
    const int g = blockIdx.x * 256 + threadIdx.x;
    if (g >= NB * SC2) return;
    const int b  = g / SC2;               // one magic-mul divide
    const int sc = g - b * SC2;
    const int t0 = blockIdx.y * TT;       // wave-uniform

    // 12 initial-window float2 loads (coalesced per k; stay L2-resident since
    // stores are non-temporal).
    const float2* ip = in + ((size_t)(b * IN_LEN + (IN_LEN - Q)) * SC2 + sc);
    float2 x[Q];
#pragma unroll
    for (int k = 0; k < Q; ++k) x[k] = ip[(size_t)k * SC2];

    float2* op = out + ((size_t)(b * OUT_LEN + t0) * SC2 + sc);

    // 84 t-steps as 7 outer iterations x fully-unrolled 12: bounded I-cache,
    // coefficients are wave-uniform -> scalar (s_load) reads.
    for (int jo = 0; jo < TT / 12; ++jo) {
#pragma unroll
        for (int ji = 0; ji < 12; ++ji) {
            const int j = jo * 12 + ji;
            float ax = 0.0f, ay = 0.0f;
#pragma unroll
            for (int k = 0; k < Q; ++k) {
                const float ck = g_coef.c[t0 + j][k];
                ax = fmaf(ck, x[k].x, ax);
                ay = fmaf(ck, x[k].y, ay);
            }
            // Non-temporal 8B store: 512B/wave contiguous, evict-first in L2.
            union { float2 f2; double d; } u;
            u.f2 = make_float2(ax, ay);
            __builtin_nontemporal_store(u.d,
                reinterpret_cast<double*>(op + (size_t)j * SC2));
        }
    }
}

extern "C" void kernel_launch(void* const* d_in, const int* in_sizes, int n_in,
                              void* d_out, int out_size, void* d_ws, size_t ws_size,
                              hipStream_t stream) {
    const float2* in = (const float2*)d_in[0];
    float2* out = (float2*)d_out;
    dim3 grid((NB * SC2 + 255) / 256,   // 324
              OUT_LEN / TT,             // 4    -> 1296 blocks (~5/CU, ~20 waves/CU)
              1);
    SimpleMovingAverage_22144851378808_kernel<<<grid, 256, 0, stream>>>(in, out);
}

// Round 3
// 338.239 us; speedup vs baseline: 1.0517x; 1.0517x over previous
//
#include <hip/hip_runtime.h>

// SimpleMovingAverage: history (64, 336, 862, 3) f32 -> out (64, 336, 862, 3).
// The scan is LINEAR in the last-12 window: out[b,t,sc] = sum_k coef[t][k]*x[b,k,sc].
// coef is input-independent -> computed at COMPILE TIME into __constant__ memory.
// Write-BW-bound op: 222 MB out (mandatory), 8 MB in (mandatory); roofline ~45us
// at the in-situ-measured 6.4 TB/s write ceiling (harness fill dispatches).
// R2: A/B — revert nontemporal stores -> regular stores (fill kernel proves
//     regular stores hit 80% of peak; NT was the only untested R1 change and
//     the only suspect for the 341->355.7 delta). Keep TT=84.

#define Q 12
#define IN_LEN 336
#define OUT_LEN 336
#define NB 64
#define SC2 1293        // SC/2 in float2 units (862*3/2)
#define TT 84           // t-values per thread (336 = 4*84)

struct Coefs { float c[OUT_LEN][Q]; };

// Compile-time evaluation of the recurrence on the 12 basis vectors.
constexpr Coefs make_coefs() {
    Coefs tbl{};
    for (int k = 0; k < Q; ++k) {
        float w[Q] = {};
        w[k] = 1.0f;
        float sum = 1.0f;
        for (int step = 0; step < OUT_LEN; ++step) {
            const int j = step % Q;
            const float m = sum * (1.0f / 12.0f);
            sum += m - w[j];         // drop oldest, append mean
            w[j] = m;
            tbl.c[step][k] = m;
            if (j == Q - 1) {        // re-anchor running sum: kill FP drift
                float s = 0.0f;
                for (int i = 0; i < Q; ++i) s += w[i];
                sum = s;
            }
        }
    }
    return tbl;
}

__constant__ Coefs g_coef = make_coefs();

__global__ __launch_bounds__(256) void
SimpleMovingAverage_22144851378808_kernel(const float2* __restrict__ in,
                                          float2* __restrict__ out) {
    const int g = blockIdx.x * 256 + threadIdx.x;
    if (g >= NB * SC2) return;
    const int b  = g / SC2;               // one magic-mul divide
    const int sc = g - b * SC2;
    const int t0 = blockIdx.y * TT;       // wave-uniform

    // 12 initial-window float2 loads (coalesced per k; L2/L3-resident re-reads
    // across the 4 t-chunks).
    const float2* ip = in + ((size_t)(b * IN_LEN + (IN_LEN - Q)) * SC2 + sc);
    float2 x[Q];
#pragma unroll
    for (int k = 0; k < Q; ++k) x[k] = ip[(size_t)k * SC2];

    float2* op = out + ((size_t)(b * OUT_LEN + t0) * SC2 + sc);

    // 84 t-steps as 7 outer iterations x fully-unrolled 12: bounded I-cache,
    // coefficients are wave-uniform -> scalar (s_load) reads.
    for (int jo = 0; jo < TT / 12; ++jo) {
#pragma unroll
        for (int ji = 0; ji < 12; ++ji) {
            const int j = jo * 12 + ji;
            float ax = 0.0f, ay = 0.0f;
#pragma unroll
            for (int k = 0; k < Q; ++k) {
                const float ck = g_coef.c[t0 + j][k];
                ax = fmaf(ck, x[k].x, ax);
                ay = fmaf(ck, x[k].y, ay);
            }
            // Regular 8B store: 512B/wave contiguous; L2 writeback path is the
            // proven-6.4TB/s route (harness fill counters).
            op[(size_t)j * SC2] = make_float2(ax, ay);
        }
    }
}

extern "C" void kernel_launch(void* const* d_in, const int* in_sizes, int n_in,
                              void* d_out, int out_size, void* d_ws, size_t ws_size,
                              hipStream_t stream) {
    const float2* in = (const float2*)d_in[0];
    float2* out = (float2*)d_out;
    dim3 grid((NB * SC2 + 255) / 256,   // 324
              OUT_LEN / TT,             // 4    -> 1296 blocks (~5/CU, ~20 waves/CU)
              1);
    SimpleMovingAverage_22144851378808_kernel<<<grid, 256, 0, stream>>>(in, out);
}